// Round 4
// baseline (5733.858 us; speedup 1.0000x reference)
//
#include <hip/hip_runtime.h>

#define H    512
#define DOBS 256
#define BATCH 32
#define SEQ  2048
#define NSLICE 8   // WGs per chain
#define NS 64      // outputs per WG

typedef float f8 __attribute__((ext_vector_type(8)));

#define PLD(p)    __hip_atomic_load((p), __ATOMIC_RELAXED, __HIP_MEMORY_SCOPE_AGENT)
#define PST(p, v) __hip_atomic_store((p), (v), __ATOMIC_RELAXED, __HIP_MEMORY_SCOPE_AGENT)

// ---------------- C[M][N] = A[M][K] @ B[N][K]^T + bias[N] ----------------
// 128x128 tile, 8x8 accumulators (round-3 verified; used for xp only now).
__global__ __launch_bounds__(256) void gemm_bias_k(const float* __restrict__ A,
                                                   const float* __restrict__ B,
                                                   const float* __restrict__ bias,
                                                   float* __restrict__ C,
                                                   int M, int N, int K) {
  __shared__ float As[16][132];
  __shared__ float Bs[16][132];
  const int m0 = blockIdx.x * 128;
  const int n0 = blockIdx.y * 128;
  const int t  = threadIdx.x;
  const int tm = (t >> 4) * 4;
  const int tn = (t & 15) * 4;
  const int lrow = t >> 2;
  const int lcol = (t & 3) * 4;

  float acc[8][8] = {};

  for (int k0 = 0; k0 < K; k0 += 16) {
    float4 a0 = *(const float4*)&A[(size_t)(m0 + lrow)      * K + k0 + lcol];
    float4 a1 = *(const float4*)&A[(size_t)(m0 + lrow + 64) * K + k0 + lcol];
    float4 b0 = *(const float4*)&B[(size_t)(n0 + lrow)      * K + k0 + lcol];
    float4 b1 = *(const float4*)&B[(size_t)(n0 + lrow + 64) * K + k0 + lcol];
    __syncthreads();
    As[lcol + 0][lrow] = a0.x; As[lcol + 1][lrow] = a0.y;
    As[lcol + 2][lrow] = a0.z; As[lcol + 3][lrow] = a0.w;
    As[lcol + 0][lrow + 64] = a1.x; As[lcol + 1][lrow + 64] = a1.y;
    As[lcol + 2][lrow + 64] = a1.z; As[lcol + 3][lrow + 64] = a1.w;
    Bs[lcol + 0][lrow] = b0.x; Bs[lcol + 1][lrow] = b0.y;
    Bs[lcol + 2][lrow] = b0.z; Bs[lcol + 3][lrow] = b0.w;
    Bs[lcol + 0][lrow + 64] = b1.x; Bs[lcol + 1][lrow + 64] = b1.y;
    Bs[lcol + 2][lrow + 64] = b1.z; Bs[lcol + 3][lrow + 64] = b1.w;
    __syncthreads();
#pragma unroll
    for (int k = 0; k < 16; ++k) {
      float4 aA = *(const float4*)&As[k][tm];
      float4 aB = *(const float4*)&As[k][tm + 64];
      float4 bA = *(const float4*)&Bs[k][tn];
      float4 bB = *(const float4*)&Bs[k][tn + 64];
      float av[8] = {aA.x, aA.y, aA.z, aA.w, aB.x, aB.y, aB.z, aB.w};
      float bv[8] = {bA.x, bA.y, bA.z, bA.w, bB.x, bB.y, bB.z, bB.w};
#pragma unroll
      for (int i = 0; i < 8; ++i)
#pragma unroll
        for (int j = 0; j < 8; ++j)
          acc[i][j] = fmaf(av[i], bv[j], acc[i][j]);
    }
  }

  float4 bbA = *(const float4*)&bias[n0 + tn];
  float4 bbB = *(const float4*)&bias[n0 + tn + 64];
#pragma unroll
  for (int i = 0; i < 8; ++i) {
    int row = m0 + ((i < 4) ? (tm + i) : (64 + tm + i - 4));
    float4 c0, c1;
    c0.x = acc[i][0] + bbA.x; c0.y = acc[i][1] + bbA.y;
    c0.z = acc[i][2] + bbA.z; c0.w = acc[i][3] + bbA.w;
    c1.x = acc[i][4] + bbB.x; c1.y = acc[i][5] + bbB.y;
    c1.z = acc[i][6] + bbB.z; c1.w = acc[i][7] + bbB.w;
    *(float4*)&C[(size_t)row * N + n0 + tn]      = c0;
    *(float4*)&C[(size_t)row * N + n0 + tn + 64] = c1;
  }
}

// ---------------- fused recurrence + output projection --------------------
// 32 chains x 8 slices (verified poll protocol: per-wave 128-chunk, 2 dwords/
// lane, h+1 >= 1.0 flags, agent scope). New structure:
//  * full-output layout: 4-lane group owns output n; lane c covers
//    k in [128c,128c+128). Weights row-major in VGPRs (Whh 128 + Woh 128).
//    Reduce = 2x shfl_xor. No sh_part, no wave0 finalize bottleneck.
//  * LDS h double-buffered by step parity (intra-WG race: wave A's bcast of
//    h_t vs wave B's z-read of h_{t-1} -> different buffers; A can only reuse
//    a buffer after crossing barrier(t+1), which B crosses after its z-read).
//  * chunk stride 132 words: bcast writes 2-way (free); group reads hit 16
//    distinct banks, 16-lane broadcast -> conflict-free.
//  * fused z = Woh @ h_{t-1} + bo computed AFTER publishing h_t (off the
//    critical path, overlaps the early-issued next poll). Stored over
//    exchange row t-2 at step t post-barrier. SAFETY: post-barrier(t) => all
//    chunks of flags(t-1) observed => all 8 WGs finalized t-1 => all passed
//    barrier(t-1) => all waves read row t-2. Last row's z goes to ws scratch
//    (its flags must survive peer epilogues); softmax redirects that row.
__global__ __launch_bounds__(256, 1) void rnn_rec_k(float* __restrict__ hid,
                                                    float* __restrict__ exch,
                                                    const float* __restrict__ Whh,
                                                    const float* __restrict__ bh,
                                                    const float* __restrict__ Woh,
                                                    const float* __restrict__ bo,
                                                    float* __restrict__ zlast) {
  const int b     = blockIdx.x & (BATCH - 1);   // spacing 32: chain stays on one XCD
  const int slice = blockIdx.x >> 5;
  const int n0    = slice * NS;
  const int tid   = threadIdx.x;
  const int w     = tid >> 6;       // wave 0..3: polls k-chunk w (128 wide)
  const int l     = tid & 63;
  const int c     = l & 3;          // k-chunk covered by this lane's FMA
  const int g     = l >> 2;         // output index within wave (0..15)
  const int n     = n0 + w * 16 + g;
  const bool lead = (c == 0);

  __shared__ __align__(16) float shh[2][4 * 132];

  float* hb = hid  + (size_t)b * SEQ * H;
  float* eb = exch + (size_t)b * SEQ * H;

  // row-major weight preload: W*[n][c*128 + 8i + j]
  f8 Wh[16], Wo[16];
  {
    const float* ph = Whh + (size_t)n * H + c * 128;
    const float* po = Woh + (size_t)n * H + c * 128;
#pragma unroll
    for (int i = 0; i < 16; ++i) {
      Wh[i] = *(const f8*)(ph + 8 * i);
      Wo[i] = *(const f8*)(po + 8 * i);
    }
  }
  const float bnh = bh[n];
  const float bno = bo[n];

  float xp_cur = hb[n];          // xp row 0 (gemm1 output)
  float xp_nxt = 0.f;
  float v0 = 0.f, v1 = 0.f;      // early-issued poll values
  float zheld = 0.f;             // z_{t-1}, stored at step t+1 (leads)

  for (int t = 0; t < SEQ; ++t) {
    float* buf = shh[t & 1];
    if (t > 0) {
      const float* ep = eb + (size_t)(t - 1) * H + w * 128;
      while (__any(!(v0 >= 1.0f && v1 >= 1.0f))) {
        v0 = PLD(ep + l);
        v1 = PLD(ep + 64 + l);
      }
      buf[w * 132 + l]      = v0 - 1.0f;
      buf[w * 132 + 64 + l] = v1 - 1.0f;
      asm volatile("s_waitcnt lgkmcnt(0)" ::: "memory");
      __builtin_amdgcn_s_barrier();
      asm volatile("" ::: "memory");
      // z_{t-2} overwrite of exchange row t-2 (certified safe post-barrier)
      if (t >= 2 && lead) eb[(size_t)(t - 2) * H + n] = zheld;
    }

    // h_t for this group's output n
    float r = 0.f;
    if (t > 0) {
      const float4* hp = (const float4*)(buf + c * 132);
      float a0 = 0.f, a1 = 0.f, a2 = 0.f, a3 = 0.f;
#pragma unroll
      for (int i = 0; i < 16; ++i) {
        float4 hA = hp[2 * i];
        float4 hB = hp[2 * i + 1];
        a0 = fmaf(Wh[i][0], hA.x, a0);
        a1 = fmaf(Wh[i][1], hA.y, a1);
        a2 = fmaf(Wh[i][2], hA.z, a2);
        a3 = fmaf(Wh[i][3], hA.w, a3);
        a0 = fmaf(Wh[i][4], hB.x, a0);
        a1 = fmaf(Wh[i][5], hB.y, a1);
        a2 = fmaf(Wh[i][6], hB.z, a2);
        a3 = fmaf(Wh[i][7], hB.w, a3);
      }
      r = (a0 + a1) + (a2 + a3);
      r += __shfl_xor(r, 1, 64);
      r += __shfl_xor(r, 2, 64);
    }
    if (lead) {
      float hv = fmaxf(r + xp_cur + bnh, 0.f);
      PST(&eb[(size_t)t * H + n], hv + 1.0f);  // publish h+1 for peers
      hb[(size_t)t * H + n] = hv;              // clean h (hidden_arr)
    }

    // early-issue next step's poll + xp load; z-FMA below overlaps the flight
    {
      const float* ep = eb + (size_t)t * H + w * 128;
      v0 = PLD(ep + l);
      v1 = PLD(ep + 64 + l);
      if (t + 1 < SEQ) xp_nxt = hb[(size_t)(t + 1) * H + n];
    }

    // fused output projection: z_{t-1} = Woh @ h_{t-1} + bo (off-path)
    if (t > 0) {
      const float4* hp = (const float4*)(buf + c * 132);
      float a0 = 0.f, a1 = 0.f, a2 = 0.f, a3 = 0.f;
#pragma unroll
      for (int i = 0; i < 16; ++i) {
        float4 hA = hp[2 * i];
        float4 hB = hp[2 * i + 1];
        a0 = fmaf(Wo[i][0], hA.x, a0);
        a1 = fmaf(Wo[i][1], hA.y, a1);
        a2 = fmaf(Wo[i][2], hA.z, a2);
        a3 = fmaf(Wo[i][3], hA.w, a3);
        a0 = fmaf(Wo[i][4], hB.x, a0);
        a1 = fmaf(Wo[i][5], hB.y, a1);
        a2 = fmaf(Wo[i][6], hB.z, a2);
        a3 = fmaf(Wo[i][7], hB.w, a3);
      }
      float zr = (a0 + a1) + (a2 + a3);
      zr += __shfl_xor(zr, 1, 64);
      zr += __shfl_xor(zr, 2, 64);
      zheld = zr + bno;
    }
    xp_cur = xp_nxt;
  }

  // ---- epilogue: z_{SEQ-2} and z_{SEQ-1} ----
  {
    float* buf = shh[SEQ & 1];
    const float* ep = eb + (size_t)(SEQ - 1) * H + w * 128;
    while (__any(!(v0 >= 1.0f && v1 >= 1.0f))) {
      v0 = PLD(ep + l);
      v1 = PLD(ep + 64 + l);
    }
    buf[w * 132 + l]      = v0 - 1.0f;
    buf[w * 132 + 64 + l] = v1 - 1.0f;
    asm volatile("s_waitcnt lgkmcnt(0)" ::: "memory");
    __builtin_amdgcn_s_barrier();
    asm volatile("" ::: "memory");
    // all WGs finalized SEQ-1 => all read row SEQ-2 => safe to overwrite
    if (lead) eb[(size_t)(SEQ - 2) * H + n] = zheld;

    const float4* hp = (const float4*)(buf + c * 132);
    float a0 = 0.f, a1 = 0.f, a2 = 0.f, a3 = 0.f;
#pragma unroll
    for (int i = 0; i < 16; ++i) {
      float4 hA = hp[2 * i];
      float4 hB = hp[2 * i + 1];
      a0 = fmaf(Wo[i][0], hA.x, a0);
      a1 = fmaf(Wo[i][1], hA.y, a1);
      a2 = fmaf(Wo[i][2], hA.z, a2);
      a3 = fmaf(Wo[i][3], hA.w, a3);
      a0 = fmaf(Wo[i][4], hB.x, a0);
      a1 = fmaf(Wo[i][5], hB.y, a1);
      a2 = fmaf(Wo[i][6], hB.z, a2);
      a3 = fmaf(Wo[i][7], hB.w, a3);
    }
    float zr = (a0 + a1) + (a2 + a3);
    zr += __shfl_xor(zr, 1, 64);
    zr += __shfl_xor(zr, 2, 64);
    // z_{SEQ-1} -> ws scratch (row SEQ-1 flags must survive peer epilogues)
    if (lead) zlast[(size_t)b * H + n] = zr + bno;
  }
}

// ---------------- in-place row softmax over 512 cols ----------------
// Last timestep's pre-softmax row lives in ws scratch (see rnn_rec_k).
__global__ __launch_bounds__(256) void softmax_k(float* __restrict__ Z,
                                                 const float* __restrict__ zlast) {
  __shared__ float smax[4];
  __shared__ float ssum[4];
  const int r  = blockIdx.x;
  const int bb = r >> 11;          // r / SEQ
  const int tt = r & (SEQ - 1);    // r % SEQ
  float* row = Z + (size_t)r * H;
  const float* src = (tt == SEQ - 1) ? (zlast + (size_t)bb * H) : row;
  const int t = threadIdx.x;
  float2 v = *(const float2*)&src[2 * t];
  float m = fmaxf(v.x, v.y);
#pragma unroll
  for (int o = 32; o > 0; o >>= 1) m = fmaxf(m, __shfl_xor(m, o, 64));
  const int wave = t >> 6, lane = t & 63;
  if (lane == 0) smax[wave] = m;
  __syncthreads();
  m = fmaxf(fmaxf(smax[0], smax[1]), fmaxf(smax[2], smax[3]));
  const float LOG2E = 1.44269504088896f;
  float ex = exp2f((v.x - m) * LOG2E);
  float ey = exp2f((v.y - m) * LOG2E);
  float s = ex + ey;
#pragma unroll
  for (int o = 32; o > 0; o >>= 1) s += __shfl_xor(s, o, 64);
  if (lane == 0) ssum[wave] = s;
  __syncthreads();
  float inv = 1.0f / (ssum[0] + ssum[1] + ssum[2] + ssum[3]);
  float2 out;
  out.x = ex * inv;
  out.y = ey * inv;
  *(float2*)&row[2 * t] = out;
}

extern "C" void kernel_launch(void* const* d_in, const int* in_sizes, int n_in,
                              void* d_out, int out_size, void* d_ws, size_t ws_size,
                              hipStream_t stream) {
  const float* x     = (const float*)d_in[0];
  const float* Whx_w = (const float*)d_in[1];
  const float* Whx_b = (const float*)d_in[2];
  const float* Whh_w = (const float*)d_in[3];
  const float* Whh_b = (const float*)d_in[4];
  const float* Woh_w = (const float*)d_in[5];
  const float* Woh_b = (const float*)d_in[6];

  float* y     = (float*)d_out;                           // output_arr; doubles as h+1 exchange, then z
  float* hid   = (float*)d_out + (size_t)BATCH * SEQ * H; // hidden_arr: xp then h
  float* zlast = (float*)d_ws;                            // 64 KB: z for t = SEQ-1

  const int M = BATCH * SEQ;  // 65536

  gemm_bias_k<<<dim3(M / 128, H / 128), 256, 0, stream>>>(x, Whx_w, Whx_b, hid, M, H, DOBS);
  rnn_rec_k<<<BATCH * NSLICE, 256, 0, stream>>>(hid, y, Whh_w, Whh_b, Woh_w, Woh_b, zlast);
  softmax_k<<<M, 256, 0, stream>>>(y, zlast);
}